// Round 4
// baseline (169.736 us; speedup 1.0000x reference)
//
#include <hip/hip_runtime.h>

// PooledMSELoss: mean((box9(pred) - box9(target))^2) = mean(box9(pred-tgt)^2)
// B,C,T,H,W = 4,2,8,512,512 fp32; POOL=9, zero pad on H,W, /81 per smooth.
//
// R4: high-occupancy chunk decomposition (4096 blocks, 8-row chunk each,
// 6 blocks/CU) + two pinned 16-load batches per thread (sched_barrier(0))
// so loads issue back-to-back with live destinations (MLP 16), within a
// VGPR budget (<85) that keeps 24 waves/CU resident.
// Evidence: R2 replay passes with data fully L3-resident ran the SAME time
// -> latency/concurrency-bound, not HBM-BW-bound. Occupancy x MLP is the fix.

constexpr int Hh    = 512;
constexpr int Ww    = 512;
constexpr int PAD   = 4;            // POOL/2
constexpr int CHUNK = 8;            // output rows per block
constexpr int LROW  = Ww + 2 * PAD; // 520 floats per LDS row

__global__ __launch_bounds__(256, 6)
void pooled_mse_kernel(const float* __restrict__ pred,
                       const float* __restrict__ tgt,
                       float* __restrict__ out) {
    __shared__ float lds[CHUNK][LROW];
    __shared__ float wsum[4];

    const int tid = threadIdx.x;
    const int img = blockIdx.x >> 6;            // 64 chunks per image
    const int sy  = (blockIdx.x & 63) * CHUNK;  // first output row

    const size_t ibase = (size_t)img * Hh * Ww;
    const float2* p2 = (const float2*)(pred + ibase);
    const float2* t2 = (const float2*)(tgt + ibase);

    // Zero the horizontal halos (never overwritten afterwards).
    if (tid < CHUNK) {
        #pragma unroll
        for (int k = 0; k < PAD; ++k) {
            lds[tid][k] = 0.0f;
            lds[tid][PAD + Ww + k] = 0.0f;
        }
    }

    // Vertical 9-sum accumulators for the 8 output rows.
    float2 v[CHUNK];
    #pragma unroll
    for (int k = 0; k < CHUNK; ++k) v[k] = make_float2(0.0f, 0.0f);

    float2 rp[8], rt[8];   // one 16-load batch's destinations (reused)

    // ---- Batch 1: input rows sy-4 .. sy+3 (ri = 0..7) ----
    #pragma unroll
    for (int r = 0; r < 8; ++r) {
        int y  = sy - PAD + r;
        int yc = y < 0 ? 0 : y;                 // top clamp only (y <= 511)
        size_t off = (size_t)yc * (Ww / 2) + tid;
        rp[r] = p2[off];
        rt[r] = t2[off];
    }
    __builtin_amdgcn_sched_barrier(0);          // pin: all 16 issue first
    #pragma unroll
    for (int r = 0; r < 8; ++r) {
        int y = sy - PAD + r;
        float mk = (y >= 0) ? 1.0f : 0.0f;      // zero padding rows
        float dx = (rp[r].x - rt[r].x) * mk;
        float dy = (rp[r].y - rt[r].y) * mk;
        // input row ri=r feeds output rows k <= ri (since ri-8 < 0)
        #pragma unroll
        for (int k = 0; k < CHUNK; ++k)
            if (r >= k) { v[k].x += dx; v[k].y += dy; }
    }

    // ---- Batch 2: input rows sy+4 .. sy+11 (ri = 8..15) ----
    #pragma unroll
    for (int r = 0; r < 8; ++r) {
        int y  = sy + PAD + r;
        int yc = y > Hh - 1 ? Hh - 1 : y;       // bottom clamp only (y >= 4)
        size_t off = (size_t)yc * (Ww / 2) + tid;
        rp[r] = p2[off];
        rt[r] = t2[off];
    }
    __builtin_amdgcn_sched_barrier(0);
    #pragma unroll
    for (int r = 0; r < 8; ++r) {
        int y = sy + PAD + r;
        float mk = (y < Hh) ? 1.0f : 0.0f;
        float dx = (rp[r].x - rt[r].x) * mk;
        float dy = (rp[r].y - rt[r].y) * mk;
        // input row ri=8+r feeds output rows k >= ri-8 = r
        #pragma unroll
        for (int k = 0; k < CHUNK; ++k)
            if (k >= r) { v[k].x += dx; v[k].y += dy; }
    }

    // Vertical sums -> LDS rows.
    #pragma unroll
    for (int k = 0; k < CHUNK; ++k) {
        lds[k][PAD + 2 * tid]     = v[k].x;
        lds[k][PAD + 2 * tid + 1] = v[k].y;
    }
    __syncthreads();

    // Horizontal 9-sums + accumulate squares.
    float acc = 0.0f;
    #pragma unroll
    for (int r = 0; r < CHUNK; ++r) {
        float s[10];
        #pragma unroll
        for (int k = 0; k < 10; ++k) s[k] = lds[r][2 * tid + k];
        float t8 = s[1];
        #pragma unroll
        for (int k = 2; k <= 8; ++k) t8 += s[k];
        float o0 = t8 + s[0];   // column 2*tid
        float o1 = t8 + s[9];   // column 2*tid+1
        acc = fmaf(o0, o0, acc);
        acc = fmaf(o1, o1, acc);
    }

    // Wave shuffle reduce, cross-wave via LDS, one atomic per block.
    #pragma unroll
    for (int off = 32; off > 0; off >>= 1)
        acc += __shfl_down(acc, off, 64);

    const int wid = tid >> 6, lane = tid & 63;
    if (lane == 0) wsum[wid] = acc;
    __syncthreads();
    if (tid == 0) {
        float b = wsum[0] + wsum[1] + wsum[2] + wsum[3];
        const float scale = 1.0f / (81.0f * 81.0f * 16777216.0f);
        atomicAdd(out, b * scale);
    }
}

extern "C" void kernel_launch(void* const* d_in, const int* in_sizes, int n_in,
                              void* d_out, int out_size, void* d_ws, size_t ws_size,
                              hipStream_t stream) {
    const float* pred = (const float*)d_in[0];
    const float* tgt  = (const float*)d_in[1];
    float* out = (float*)d_out;

    // d_out is re-poisoned to 0xAA before every timed launch.
    hipMemsetAsync(out, 0, sizeof(float), stream);

    const int nblocks = 64 * (Hh / CHUNK);   // 64 images * 64 chunks = 4096
    pooled_mse_kernel<<<nblocks, 256, 0, stream>>>(pred, tgt, out);
}

// Round 5
// 168.911 us; speedup vs baseline: 1.0049x; 1.0049x over previous
//
#include <hip/hip_runtime.h>

// PooledMSELoss: mean((box9(pred) - box9(target))^2) = mean(box9(pred-tgt)^2)
// B,C,T,H,W = 4,2,8,512,512 fp32; POOL=9, zero pad on H,W, /81 per smooth.
//
// R5: force MLP with inline-asm loads. R2/R4 post-mortem: VGPR_Count=32 both
// times -> compiler sinks loads to their uses (MLP~2) no matter how the
// source is shaped; CU-level load throughput ~1 per 300cy matches. Volatile
// asm global_load_dwordx2 batches are mutually ordered with live "=v" dests,
// so all 32 loads/thread are in flight; one s_waitcnt vmcnt(0) + sched_barrier
// (rule #18 fence) before the consumers.

constexpr int Hh    = 512;
constexpr int Ww    = 512;
constexpr int PAD   = 4;            // POOL/2
constexpr int CHUNK = 8;            // output rows per block
constexpr int LROW  = Ww + 2 * PAD; // 520 floats per LDS row

typedef float v2f __attribute__((ext_vector_type(2)));

__global__ __launch_bounds__(256, 4)
void pooled_mse_kernel(const float* __restrict__ pred,
                       const float* __restrict__ tgt,
                       float* __restrict__ out) {
    __shared__ float lds[CHUNK][LROW];
    __shared__ float wsum[4];

    const int tid = threadIdx.x;
    const int img = blockIdx.x >> 6;            // 64 chunks per image
    const int sy  = (blockIdx.x & 63) * CHUNK;  // first output row

    const size_t ibase = (size_t)img * Hh * Ww;
    const float* pbase = pred + ibase;          // uniform -> SGPR pair
    const float* tbase = tgt + ibase;

    // Zero the horizontal halos (never overwritten afterwards).
    if (tid < CHUNK) {
        #pragma unroll
        for (int k = 0; k < PAD; ++k) {
            lds[tid][k] = 0.0f;
            lds[tid][PAD + Ww + k] = 0.0f;
        }
    }

    // Per-row byte offsets (clamped rows; pad rows masked to zero later).
    int voff[16];
    #pragma unroll
    for (int r = 0; r < 16; ++r) {
        int y  = sy - PAD + r;
        int yc = y < 0 ? 0 : (y > Hh - 1 ? Hh - 1 : y);
        voff[r] = yc * (Ww * 4) + tid * 8;
    }

    // Issue ALL 32 loads back-to-back (volatile asm: ordered, dests live).
    v2f dp[16], dt[16];
    #pragma unroll
    for (int r = 0; r < 16; ++r) {
        asm volatile("global_load_dwordx2 %0, %1, %2"
                     : "=v"(dp[r]) : "v"(voff[r]), "s"(pbase));
        asm volatile("global_load_dwordx2 %0, %1, %2"
                     : "=v"(dt[r]) : "v"(voff[r]), "s"(tbase));
    }
    // Wait once for all 32, then fence the scheduler (rule #18: consumers
    // must not hoist above the waitcnt — "memory" doesn't order VALU).
    asm volatile("s_waitcnt vmcnt(0)" ::: "memory");
    __builtin_amdgcn_sched_barrier(0);

    // Vertical 9-sum accumulators for the 8 output rows.
    float2 v[CHUNK];
    #pragma unroll
    for (int k = 0; k < CHUNK; ++k) v[k] = make_float2(0.0f, 0.0f);

    #pragma unroll
    for (int r = 0; r < 16; ++r) {
        int y = sy - PAD + r;
        float mk = ((unsigned)y < (unsigned)Hh) ? 1.0f : 0.0f;  // zero pad
        float dx = (dp[r][0] - dt[r][0]) * mk;
        float dy = (dp[r][1] - dt[r][1]) * mk;
        // input row r (= y-(sy-4)) feeds output rows k with k <= r <= k+8
        #pragma unroll
        for (int k = 0; k < CHUNK; ++k)
            if (r >= k && r <= k + 8) { v[k].x += dx; v[k].y += dy; }
    }

    // Vertical sums -> LDS rows.
    #pragma unroll
    for (int k = 0; k < CHUNK; ++k) {
        lds[k][PAD + 2 * tid]     = v[k].x;
        lds[k][PAD + 2 * tid + 1] = v[k].y;
    }
    __syncthreads();

    // Horizontal 9-sums + accumulate squares.
    float acc = 0.0f;
    #pragma unroll
    for (int r = 0; r < CHUNK; ++r) {
        float s[10];
        #pragma unroll
        for (int k = 0; k < 10; ++k) s[k] = lds[r][2 * tid + k];
        float t8 = s[1];
        #pragma unroll
        for (int k = 2; k <= 8; ++k) t8 += s[k];
        float o0 = t8 + s[0];   // column 2*tid
        float o1 = t8 + s[9];   // column 2*tid+1
        acc = fmaf(o0, o0, acc);
        acc = fmaf(o1, o1, acc);
    }

    // Wave shuffle reduce, cross-wave via LDS, one atomic per block.
    #pragma unroll
    for (int off = 32; off > 0; off >>= 1)
        acc += __shfl_down(acc, off, 64);

    const int wid = tid >> 6, lane = tid & 63;
    if (lane == 0) wsum[wid] = acc;
    __syncthreads();
    if (tid == 0) {
        float b = wsum[0] + wsum[1] + wsum[2] + wsum[3];
        const float scale = 1.0f / (81.0f * 81.0f * 16777216.0f);
        atomicAdd(out, b * scale);
    }
}

extern "C" void kernel_launch(void* const* d_in, const int* in_sizes, int n_in,
                              void* d_out, int out_size, void* d_ws, size_t ws_size,
                              hipStream_t stream) {
    const float* pred = (const float*)d_in[0];
    const float* tgt  = (const float*)d_in[1];
    float* out = (float*)d_out;

    // d_out is re-poisoned to 0xAA before every timed launch.
    hipMemsetAsync(out, 0, sizeof(float), stream);

    const int nblocks = 64 * (Hh / CHUNK);   // 64 images * 64 chunks = 4096
    pooled_mse_kernel<<<nblocks, 256, 0, stream>>>(pred, tgt, out);
}

// Round 6
// 166.512 us; speedup vs baseline: 1.0194x; 1.0144x over previous
//
#include <hip/hip_runtime.h>
#include <cstdint>

// PooledMSELoss: mean((box9(pred) - box9(target))^2) = mean(box9(pred-tgt)^2)
// B,C,T,H,W = 4,2,8,512,512 fp32; POOL=9, zero pad on H,W, /81 per smooth.
//
// R6: global_load_lds DMA staging. R2/R4/R5 post-mortem: any scheme whose
// load results land in VGPRs gets collapsed to MLP~2 by the compiler
// (VGPR_Count 32/32/36 across three structures; all 66us, 2.0 TB/s).
// global_load_lds has NO destination registers -> 16 DMAs/wave stay in
// flight structurally. XCD swizzle keeps vertically-adjacent chunks (shared
// halo rows) on one XCD's L2.

constexpr int Hh    = 512;
constexpr int Ww    = 512;
constexpr int PAD   = 4;            // POOL/2
constexpr int CHUNK = 8;            // output rows per block
constexpr int NROW  = 16;           // staged input rows per block
constexpr int LROW  = Ww + 2 * PAD; // 520 floats per s9 row

__device__ __forceinline__ void dma16(const float* g, float* l) {
    // 64 lanes x 16B -> LDS at (wave-uniform base) + lane*16. CK-style casts.
    auto gp = (const __attribute__((address_space(1))) void*)g;
    auto lp = (__attribute__((address_space(3))) void*)(uintptr_t)l;
    __builtin_amdgcn_global_load_lds(gp, lp, 16, 0, 0);
}

__global__ __launch_bounds__(256, 2)
void pooled_mse_kernel(const float* __restrict__ pred,
                       const float* __restrict__ tgt,
                       float* __restrict__ out) {
    __shared__ float sp[NROW * Ww];   // 32 KB raw pred rows
    __shared__ float st[NROW * Ww];   // 32 KB raw tgt rows; later s9 overlay
    __shared__ float wsum[4];

    const int tid = threadIdx.x;

    // Bijective XCD swizzle (4096 % 8 == 0): consecutive work ids (adjacent
    // row-chunks of one image) land on the same XCD -> halo rows L2-hit.
    const int nwg = 64 * (Hh / CHUNK);            // 4096
    const int wg  = (blockIdx.x & 7) * (nwg >> 3) + (blockIdx.x >> 3);
    const int img = wg >> 6;                      // 64 chunks per image
    const int sy  = (wg & 63) * CHUNK;            // first output row

    const float* pb = pred + (size_t)img * Hh * Ww;
    const float* tb = tgt  + (size_t)img * Hh * Ww;

    // ---- Stage: 16 rows of pred + 16 rows of tgt, 32 async DMAs ----
    // Issue-group j covers rows 2j,2j+1 (4 KB): this thread supplies 16 B
    // from row y = sy-4+2j+(tid>>7), col 4*(tid&127); LDS dest is the
    // wave-uniform slot (tid>>6)*256 floats within the group.
    const int rhalf = tid >> 7;                   // 0/1: which row of pair
    const int c4    = (tid & 127) * 4;            // starting column
    const int lslot = (tid >> 6) * 256;           // floats, uniform per wave

    #pragma unroll
    for (int j = 0; j < NROW / 2; ++j) {
        int y  = sy - PAD + 2 * j + rhalf;
        int yc = y < 0 ? 0 : (y > Hh - 1 ? Hh - 1 : y);   // clamp (mask later)
        const size_t goff = (size_t)yc * Ww + c4;
        dma16(pb + goff, &sp[j * 1024 + lslot]);
        dma16(tb + goff, &st[j * 1024 + lslot]);
    }
    __builtin_amdgcn_s_waitcnt(0);    // all 32 DMAs landed
    __syncthreads();

    // ---- Diff + vertical 9-sums (thread owns cols 2*tid, 2*tid+1) ----
    float2 v[CHUNK];
    #pragma unroll
    for (int k = 0; k < CHUNK; ++k) v[k] = make_float2(0.0f, 0.0f);

    const float2* sp2 = (const float2*)sp;
    const float2* st2 = (const float2*)st;
    #pragma unroll
    for (int r = 0; r < NROW; ++r) {
        int y = sy - PAD + r;
        float mk = ((unsigned)y < (unsigned)Hh) ? 1.0f : 0.0f;  // zero pad
        float2 a = sp2[r * 256 + tid];
        float2 b = st2[r * 256 + tid];
        float dx = (a.x - b.x) * mk;
        float dy = (a.y - b.y) * mk;
        #pragma unroll
        for (int k = 0; k < CHUNK; ++k)
            if (r >= k && r <= k + 8) { v[k].x += dx; v[k].y += dy; }
    }
    __syncthreads();   // all reads of st done before s9 overlay

    // ---- s9 overlay on st: [CHUNK][LROW] with zero halos ----
    float* s9 = st;
    if (tid < CHUNK) {
        #pragma unroll
        for (int k = 0; k < PAD; ++k) {
            s9[tid * LROW + k] = 0.0f;
            s9[tid * LROW + PAD + Ww + k] = 0.0f;
        }
    }
    #pragma unroll
    for (int k = 0; k < CHUNK; ++k) {
        s9[k * LROW + PAD + 2 * tid]     = v[k].x;
        s9[k * LROW + PAD + 2 * tid + 1] = v[k].y;
    }
    __syncthreads();

    // ---- Horizontal 9-sums + accumulate squares ----
    float acc = 0.0f;
    #pragma unroll
    for (int r = 0; r < CHUNK; ++r) {
        float s[10];
        #pragma unroll
        for (int k = 0; k < 10; ++k) s[k] = s9[r * LROW + 2 * tid + k];
        float t8 = s[1];
        #pragma unroll
        for (int k = 2; k <= 8; ++k) t8 += s[k];
        float o0 = t8 + s[0];   // column 2*tid
        float o1 = t8 + s[9];   // column 2*tid+1
        acc = fmaf(o0, o0, acc);
        acc = fmaf(o1, o1, acc);
    }

    // ---- Wave shuffle reduce, cross-wave via LDS, one atomic per block ----
    #pragma unroll
    for (int off = 32; off > 0; off >>= 1)
        acc += __shfl_down(acc, off, 64);

    const int wid = tid >> 6, lane = tid & 63;
    if (lane == 0) wsum[wid] = acc;
    __syncthreads();
    if (tid == 0) {
        float b = wsum[0] + wsum[1] + wsum[2] + wsum[3];
        const float scale = 1.0f / (81.0f * 81.0f * 16777216.0f);
        atomicAdd(out, b * scale);
    }
}

extern "C" void kernel_launch(void* const* d_in, const int* in_sizes, int n_in,
                              void* d_out, int out_size, void* d_ws, size_t ws_size,
                              hipStream_t stream) {
    const float* pred = (const float*)d_in[0];
    const float* tgt  = (const float*)d_in[1];
    float* out = (float*)d_out;

    // d_out is re-poisoned to 0xAA before every timed launch.
    hipMemsetAsync(out, 0, sizeof(float), stream);

    const int nblocks = 64 * (Hh / CHUNK);   // 4096
    pooled_mse_kernel<<<nblocks, 256, 0, stream>>>(pred, tgt, out);
}